// Round 4
// baseline (338.176 us; speedup 1.0000x reference)
//
#include <hip/hip_runtime.h>

typedef unsigned short u16;
typedef short s16x8 __attribute__((ext_vector_type(8)));
typedef float f32x4 __attribute__((ext_vector_type(4)));

#define ALPHA 0.18033688f          /* 0.125 * log2(e) : folded into Q */
#define MASKC -1.44269504e9f      /* -1e9 * log2(e) */

// ---------------- bf16 helpers (RNE) ----------------
static __device__ __forceinline__ u16 f2b(float f) {
  union { float f; unsigned u; } v; v.f = f;
  unsigned r = v.u + 0x7fffu + ((v.u >> 16) & 1u);
  return (u16)(r >> 16);
}
static __device__ __forceinline__ float b2f(u16 u) {
  union { unsigned u; float f; } v; v.u = ((unsigned)u) << 16;
  return v.f;
}
static __device__ __forceinline__ float exp2_hw(float x) {
  float r; asm("v_exp_f32 %0, %1" : "=v"(r) : "v"(x)); return r;
}

#define MFMA16(a, b, c) __builtin_amdgcn_mfma_f32_16x16x32_bf16((a), (b), (c), 0, 0, 0)

// async global -> LDS, 16B per lane (dest = uniform base + lane*16)
static __device__ __forceinline__ void gload_lds16(const u16* g, u16* l) {
  __builtin_amdgcn_global_load_lds((const __attribute__((address_space(1))) void*)g,
                                   (__attribute__((address_space(3))) void*)l, 16, 0, 0);
}

// ---------------- prep kernels ----------------
__global__ void k_cast_x(const float* __restrict__ src, u16* __restrict__ dst, int n4) {
  int i = blockIdx.x * blockDim.x + threadIdx.x;
  if (i >= n4) return;
  float4 v = ((const float4*)src)[i];
  ushort4 o;
  o.x = f2b(v.x); o.y = f2b(v.y); o.z = f2b(v.z); o.w = f2b(v.w);
  ((ushort4*)dst)[i] = o;
}

// W [1024 u][1024 n] f32 -> Wt [1024 n][1024 u] bf16
__global__ void k_transpose_w(const float* wq, const float* wk, const float* wv, const float* wo,
                              u16* dq, u16* dk, u16* dv, u16* dwo) {
  const float* src; u16* dst;
  int z = blockIdx.z;
  if (z == 0)      { src = wq; dst = dq; }
  else if (z == 1) { src = wk; dst = dk; }
  else if (z == 2) { src = wv; dst = dv; }
  else             { src = wo; dst = dwo; }
  __shared__ float t[32][33];
  int x0 = blockIdx.x * 32, y0 = blockIdx.y * 32;
  int tx = threadIdx.x, ty = threadIdx.y;
#pragma unroll
  for (int k = 0; k < 4; k++) t[ty + 8 * k][tx] = src[(size_t)(y0 + ty + 8 * k) * 1024 + x0 + tx];
  __syncthreads();
#pragma unroll
  for (int k = 0; k < 4; k++) dst[(size_t)(x0 + ty + 8 * k) * 1024 + y0 + tx] = f2b(t[tx][ty + 8 * k]);
}

// ekb: [16][144][64] bf16 ; evt: [16][64][160] bf16 (ev^T) ; maskb: [4][1024] bf16 additive (log2-domain)
__global__ void k_prep_rel(const float* __restrict__ ek, const float* __restrict__ ev,
                           const float* __restrict__ pm,
                           u16* __restrict__ ekb, u16* __restrict__ evt, u16* __restrict__ maskb) {
  int i = blockIdx.x * blockDim.x + threadIdx.x;
  if (i < 16 * 144 * 64) {
    int h = i / (144 * 64); int rem = i % (144 * 64); int m = rem / 64; int d = rem % 64;
    ekb[i] = (m < 129) ? f2b(ek[((size_t)h * 129 + m) * 64 + d]) : (u16)0;
  }
  if (i < 16 * 64 * 160) {
    int h = i / (64 * 160); int rem = i % (64 * 160); int d = rem / 160; int mm = rem % 160;
    evt[i] = (mm < 129) ? f2b(ev[((size_t)h * 129 + mm) * 64 + d]) : (u16)0;
  }
  if (i < 4096) maskb[i] = f2b(pm[i] * MASKC);
}

// ---------------- bf16 MFMA GEMM: C[4096][1024] = A * Bt^T, 2-phase pipelined --------
// MODE 0: bf16 -> [B][H][L][D] (Q/K, scaled by oscale)
// MODE 1: bf16 -> [B][H][D][L] (V^T via operand-swapped MFMA -> coalesced)
// MODE 2: f32 row-major + bias
template <int MODE>
static __device__ __forceinline__ void gemm_body(const u16* __restrict__ A, const u16* __restrict__ Bt,
                                                 void* __restrict__ Cout, const float* __restrict__ bias,
                                                 float oscale, int bx, int by) {
  __shared__ u16 As[2][128 * 32];
  __shared__ u16 Bs[2][128 * 32];
  int tid = threadIdx.x;
  int w = tid >> 6, lane = tid & 63;
  int wrw = w >> 1, wcw = w & 1, lr = lane & 15, lk = lane >> 4;
  int m0 = by * 128, n0 = bx * 128;
  f32x4 acc[4][4] = {};
  int crow = lane >> 2;          // row within 16-row chunk
  int ccol = (lane & 3) * 8;     // u16 col within 32
  const u16* gA = &A [(size_t)(m0 + w * 32 + crow) * 1024 + ccol];
  const u16* gB = &Bt[(size_t)(n0 + w * 32 + crow) * 1024 + ccol];

  auto STAGE = [&](int buf, int k0) {
    u16* lA = &As[buf][w * 1024];
    u16* lB = &Bs[buf][w * 1024];
    gload_lds16(gA + k0,             lA);
    gload_lds16(gA + k0 + 16 * 1024, lA + 16 * 32);
    gload_lds16(gB + k0,             lB);
    gload_lds16(gB + k0 + 16 * 1024, lB + 16 * 32);
  };

  STAGE(0, 0);
  __syncthreads();
  int cur = 0;
  for (int t = 0; t < 32; t++) {
    if (t < 31) STAGE(cur ^ 1, (t + 1) * 32);
    s16x8 af[4], bfr[4];
#pragma unroll
    for (int mt = 0; mt < 4; mt++) af[mt]  = *(const s16x8*)&As[cur][(wrw * 64 + mt * 16 + lr) * 32 + lk * 8];
#pragma unroll
    for (int nt = 0; nt < 4; nt++) bfr[nt] = *(const s16x8*)&Bs[cur][(wcw * 64 + nt * 16 + lr) * 32 + lk * 8];
    __builtin_amdgcn_s_setprio(1);
#pragma unroll
    for (int mt = 0; mt < 4; mt++)
#pragma unroll
      for (int nt = 0; nt < 4; nt++) {
        if (MODE == 1) acc[mt][nt] = MFMA16(bfr[nt], af[mt], acc[mt][nt]);
        else           acc[mt][nt] = MFMA16(af[mt], bfr[nt], acc[mt][nt]);
      }
    __builtin_amdgcn_s_setprio(0);
    __syncthreads();
    cur ^= 1;
  }
#pragma unroll
  for (int mt = 0; mt < 4; mt++)
#pragma unroll
    for (int nt = 0; nt < 4; nt++)
#pragma unroll
      for (int r = 0; r < 4; r++) {
        float v = acc[mt][nt][r];
        if (MODE == 1) {
          int u = n0 + wcw * 64 + nt * 16 + lk * 4 + r;
          int l = m0 + wrw * 64 + mt * 16 + lr;
          int bb = l >> 10, ll = l & 1023;
          int hh = u >> 6, dd = u & 63;
          ((u16*)Cout)[((size_t)(bb * 16 + hh)) * 65536 + (size_t)dd * 1024 + ll] = f2b(v);
        } else {
          int row = m0 + wrw * 64 + mt * 16 + lk * 4 + r;
          int col = n0 + wcw * 64 + nt * 16 + lr;
          if (MODE == 2) {
            ((float*)Cout)[(size_t)row * 1024 + col] = v + bias[col];
          } else {
            int bb = row >> 10, l = row & 1023;
            int hh = col >> 6, dd = col & 63;
            ((u16*)Cout)[((size_t)(bb * 16 + hh)) * 65536 + (size_t)l * 64 + dd] = f2b(v * oscale);
          }
        }
      }
}

__global__ __launch_bounds__(256) void k_gemm_qk(const u16* __restrict__ A,
                                                 const u16* __restrict__ BtQ, const u16* __restrict__ BtK,
                                                 u16* __restrict__ Qo, u16* __restrict__ Ko) {
  const u16* Bt = blockIdx.z ? BtK : BtQ;
  u16* C        = blockIdx.z ? Ko  : Qo;
  gemm_body<0>(A, Bt, C, nullptr, blockIdx.z ? 1.0f : ALPHA, blockIdx.x, blockIdx.y);
}
__global__ __launch_bounds__(256) void k_gemm_v(const u16* __restrict__ A, const u16* __restrict__ Bt,
                                                u16* __restrict__ Vo) {
  gemm_body<1>(A, Bt, Vo, nullptr, 1.0f, blockIdx.x, blockIdx.y);
}
__global__ __launch_bounds__(256) void k_gemm_out(const u16* __restrict__ A, const u16* __restrict__ Bt,
                                                  float* __restrict__ Cout, const float* __restrict__ bias) {
  gemm_body<2>(A, Bt, Cout, bias, 1.0f, blockIdx.x, blockIdx.y);
}

// ---------------- fused relative-position attention ----------------
// 1 wave / 16-row q-tile, zero barriers, log2-domain softmax (Q pre-scaled by 0.125*log2e).
// Band classification per j-tile: LEFT (all dl<=-64) / MIXED / RIGHT (all dl>=64).
// LDS 12.75 KB -> 12 blocks/CU:
//   qm_s @ 0    : [16][136] bf16 = 4352
//   P_s  @ 4352 : [16][136] bf16 = 4352
//   wrb  @ 8704 : [16][136] bf16 = 4352  (cols 0..127 = buckets 0..127; bucket 128 rank-1)
template <int CLS>
static __device__ __forceinline__ void attn_tile(
    int j0, const u16* __restrict__ Kt, const u16* __restrict__ Vt0, const u16* __restrict__ mrow,
    s16x8 aq0, s16x8 aq1, u16* qm_s, u16* P_s, u16* wrb,
    float qmL, float qmR, int lr, int lk, int ig,
    f32x4 oacc[4], float& ssum, float& lsum, float& rsum)
{
  float p[8][4];
  const u16* kbase = Kt + (size_t)(j0 + lr) * 64 + lk * 8;
  const u16* mbase = &mrow[j0 + lk * 4];
#pragma unroll
  for (int nt = 0; nt < 8; nt++) {
    f32x4 c = {};
    const u16* kp = kbase + nt * 1024;
    c = MFMA16(*(const s16x8*)kp, aq0, c);          // swapped: rows=j, cols=i
    c = MFMA16(*(const s16x8*)(kp + 32), aq1, c);
    ushort4 mv = *(const ushort4*)(mbase + nt * 16);
#pragma unroll
    for (int r = 0; r < 4; r++) {
      float qmv;
      if (CLS == 0) qmv = qmL;
      else if (CLS == 2) qmv = qmR;
      else {
        int dl = j0 + nt * 16 + lk * 4 + r - ig;
        dl = dl < -64 ? -64 : (dl > 64 ? 64 : dl);
        qmv = b2f(qm_s[lr * 136 + dl + 64]);
      }
      float mr = b2f(r == 0 ? mv.x : r == 1 ? mv.y : r == 2 ? mv.z : mv.w);
      p[nt][r] = exp2_hw(fminf(c[r] + qmv + mr, 110.f));
    }
  }
  // pack P~ to LDS A-fragment layout: P[i=lr][j]
#pragma unroll
  for (int nt = 0; nt < 8; nt++) {
    unsigned lo, hi;
    asm("v_cvt_pk_bf16_f32 %0, %1, %2" : "=v"(lo) : "v"(p[nt][0]), "v"(p[nt][1]));
    asm("v_cvt_pk_bf16_f32 %0, %1, %2" : "=v"(hi) : "v"(p[nt][2]), "v"(p[nt][3]));
    uint2 pk; pk.x = lo; pk.y = hi;
    *(uint2*)&P_s[lr * 136 + nt * 16 + lk * 4] = pk;
  }
  // PV: oacc[i][d] += P~ . V
  __builtin_amdgcn_s_setprio(1);
  {
    s16x8 ap[4];
#pragma unroll
    for (int kk = 0; kk < 4; kk++) ap[kk] = *(const s16x8*)&P_s[lr * 136 + kk * 32 + lk * 8];
    const u16* vbase = Vt0 + (size_t)lr * 1024 + j0 + lk * 8;
#pragma unroll
    for (int nt = 0; nt < 4; nt++) {
      const u16* vp = vbase + nt * 16 * 1024;
#pragma unroll
      for (int kk = 0; kk < 4; kk++)
        oacc[nt] = MFMA16(ap[kk], *(const s16x8*)(vp + kk * 32), oacc[nt]);
    }
  }
  __builtin_amdgcn_s_setprio(0);
  // route P mass: edge sums (fast tiles) or banded scatter (mixed)
  if (CLS != 1) {
    float s01 = 0.f, s23 = 0.f;
#pragma unroll
    for (int nt = 0; nt < 8; nt++) { s01 += p[nt][0] + p[nt][1]; s23 += p[nt][2] + p[nt][3]; }
    float s = s01 + s23;
    ssum += s;
    if (CLS == 0) lsum += s; else rsum += s;
  } else {
#pragma unroll
    for (int nt = 0; nt < 8; nt++)
#pragma unroll
      for (int r = 0; r < 4; r++) {
        float pv = p[nt][r];
        ssum += pv;
        int dl = j0 + nt * 16 + lk * 4 + r - ig;
        if (dl <= -64) lsum += pv;
        else if (dl >= 64) rsum += pv;
        else wrb[lr * 136 + dl + 64] = f2b(pv);
      }
  }
}

__global__ __launch_bounds__(64) void k_attn(const u16* __restrict__ Qg, const u16* __restrict__ Kg,
                                             const u16* __restrict__ Vt, const u16* __restrict__ ekb,
                                             const u16* __restrict__ evt, const u16* __restrict__ maskb,
                                             u16* __restrict__ Og) {
  __shared__ alignas(16) char smem[13056];
  u16* qm_s = (u16*)smem;
  u16* P_s  = (u16*)(smem + 4352);
  u16* wrb  = (u16*)(smem + 8704);

  int lane = threadIdx.x;
  int lr = lane & 15, lk = lane >> 4;
  // XCD-bijective swizzle (4096 % 8 == 0): blocks sharing (b,h) land on one XCD
  int wg = (blockIdx.x & 7) * 512 + (blockIdx.x >> 3);
  int bh = wg >> 6, it = wg & 63;
  int b = bh >> 4, h = bh & 15;
  int i0 = it * 16;

  // zero wrb (16*136 u16 = 1088 dwords)
  for (int t = lane; t < 1088; t += 64) ((unsigned*)wrb)[t] = 0u;

  // Q fragments (pre-scaled by ALPHA at GEMM epilogue)
  const u16* qp = &Qg[((size_t)bh * 1024 + i0 + lr) * 64 + lk * 8];
  s16x8 aq0 = *(const s16x8*)qp;
  s16x8 aq1 = *(const s16x8*)(qp + 32);

  // qm[i][m] = q_i . ek[h][m] (log2-domain, rows i=lr as cols of swapped write)
#pragma unroll
  for (int nt = 0; nt < 9; nt++) {
    f32x4 c = {};
    const u16* ekp = &ekb[((size_t)h * 144 + nt * 16 + lr) * 64 + lk * 8];
    c = MFMA16(aq0, *(const s16x8*)ekp, c);
    c = MFMA16(aq1, *(const s16x8*)(ekp + 32), c);
    int mcol = nt * 16 + lr;
    if (mcol < 129) {
#pragma unroll
      for (int r = 0; r < 4; r++) qm_s[(lk * 4 + r) * 136 + mcol] = f2b(c[r]);
    }
  }
  float qmL = b2f(qm_s[lr * 136]);
  float qmR = b2f(qm_s[lr * 136 + 128]);

  float ssum = 0.f, lsum = 0.f, rsum = 0.f;
  f32x4 oacc[4] = {};
  const int ig = i0 + lr;
  const u16* Kt  = Kg + (size_t)bh * 65536;
  const u16* Vt0 = Vt + (size_t)bh * 65536;
  const u16* mrow = maskb + b * 1024;

  int jtL = (i0 - 64) >> 7; if (jtL < 0) jtL = 0;           // tiles < jtL fully left of band
  int jtR = (i0 + 207) >> 7; if (jtR > 8) jtR = 8;          // tiles >= jtR fully right
  for (int jt = 0; jt < jtL; jt++)
    attn_tile<0>(jt * 128, Kt, Vt0, mrow, aq0, aq1, qm_s, P_s, wrb, qmL, qmR, lr, lk, ig, oacc, ssum, lsum, rsum);
  for (int jt = jtL; jt < jtR; jt++)
    attn_tile<1>(jt * 128, Kt, Vt0, mrow, aq0, aq1, qm_s, P_s, wrb, qmL, qmR, lr, lk, ig, oacc, ssum, lsum, rsum);
  for (int jt = jtR; jt < 8; jt++)
    attn_tile<2>(jt * 128, Kt, Vt0, mrow, aq0, aq1, qm_s, P_s, wrb, qmL, qmR, lr, lk, ig, oacc, ssum, lsum, rsum);

  // reduce edge/total sums across the 4 lanes sharing lr
  lsum += __shfl_xor(lsum, 16); lsum += __shfl_xor(lsum, 32);
  rsum += __shfl_xor(rsum, 16); rsum += __shfl_xor(rsum, 32);
  ssum += __shfl_xor(ssum, 16); ssum += __shfl_xor(ssum, 32);
  if (lk == 0) wrb[lr * 136] = f2b(lsum);   // bucket 0

  // oacc += wr . Ev over buckets 0..127
  __builtin_amdgcn_s_setprio(1);
  {
    s16x8 aw[4];
#pragma unroll
    for (int kk = 0; kk < 4; kk++) aw[kk] = *(const s16x8*)&wrb[lr * 136 + kk * 32 + lk * 8];
    const u16* ebase = &evt[((size_t)h * 64 + lr) * 160 + lk * 8];
#pragma unroll
    for (int nt = 0; nt < 4; nt++) {
      const u16* ep = ebase + nt * 16 * 160;
#pragma unroll
      for (int kk = 0; kk < 4; kk++)
        oacc[nt] = MFMA16(aw[kk], *(const s16x8*)(ep + kk * 32), oacc[nt]);
    }
  }
  __builtin_amdgcn_s_setprio(0);

  // bucket 128 rank-1: oacc[i][d] += rsum[i] * ev[h][128][d]
  {
    float rs[4];
#pragma unroll
    for (int r = 0; r < 4; r++) rs[r] = __shfl(rsum, lk * 4 + r);
#pragma unroll
    for (int nt = 0; nt < 4; nt++) {
      float evc = b2f(evt[((size_t)h * 64 + nt * 16 + lr) * 160 + 128]);
#pragma unroll
      for (int r = 0; r < 4; r++) oacc[nt][r] += rs[r] * evc;
    }
  }

  // normalize + write O[(b,l)][(h,d)]
  float rden[4];
#pragma unroll
  for (int r = 0; r < 4; r++) rden[r] = 1.0f / __shfl(ssum, lk * 4 + r);
  u16* obase = &Og[((size_t)(b * 1024 + i0)) * 1024 + h * 64];
#pragma unroll
  for (int nt = 0; nt < 4; nt++)
#pragma unroll
    for (int r = 0; r < 4; r++) {
      int il = lk * 4 + r;
      obase[(size_t)il * 1024 + nt * 16 + lr] = f2b(oacc[nt][r] * rden[r]);
    }
}

// ---------------- launch ----------------
#define OFF_XB   0u
#define OFF_WQT  8388608u
#define OFF_WKT  10485760u
#define OFF_WVT  12582912u
#define OFF_WOT  14680064u
#define OFF_Q    16777216u
#define OFF_K    25165824u
#define OFF_VT   33554432u
#define OFF_O    41943040u
#define OFF_EKB  50331648u
#define OFF_EVT  50626560u
#define OFF_MB   50954240u

extern "C" void kernel_launch(void* const* d_in, const int* in_sizes, int n_in,
                              void* d_out, int out_size, void* d_ws, size_t ws_size,
                              hipStream_t stream) {
  const float* x  = (const float*)d_in[0];
  const float* pm = (const float*)d_in[1];
  const float* wq = (const float*)d_in[2];
  const float* wk = (const float*)d_in[3];
  const float* wv = (const float*)d_in[4];
  const float* wo = (const float*)d_in[5];
  const float* bo = (const float*)d_in[6];
  const float* ek = (const float*)d_in[7];
  const float* ev = (const float*)d_in[8];
  char* ws = (char*)d_ws;
  u16* Xb  = (u16*)(ws + OFF_XB);
  u16* Wqt = (u16*)(ws + OFF_WQT);
  u16* Wkt = (u16*)(ws + OFF_WKT);
  u16* Wvt = (u16*)(ws + OFF_WVT);
  u16* Wot = (u16*)(ws + OFF_WOT);
  u16* Qg  = (u16*)(ws + OFF_Q);
  u16* Kg  = (u16*)(ws + OFF_K);
  u16* Vtg = (u16*)(ws + OFF_VT);
  u16* Og  = (u16*)(ws + OFF_O);
  u16* EKB = (u16*)(ws + OFF_EKB);
  u16* EVT = (u16*)(ws + OFF_EVT);
  u16* MB  = (u16*)(ws + OFF_MB);

  k_cast_x<<<4096, 256, 0, stream>>>(x, Xb, 1048576);
  {
    dim3 tb(32, 8), tg(32, 32, 4);
    k_transpose_w<<<tg, tb, 0, stream>>>(wq, wk, wv, wo, Wqt, Wkt, Wvt, Wot);
  }
  k_prep_rel<<<640, 256, 0, stream>>>(ek, ev, pm, EKB, EVT, MB);
  {
    dim3 gqk(8, 32, 2);
    k_gemm_qk<<<gqk, 256, 0, stream>>>(Xb, Wqt, Wkt, Qg, Kg);
    dim3 gv(8, 32);
    k_gemm_v<<<gv, 256, 0, stream>>>(Xb, Wvt, Vtg);
    k_attn<<<4096, 64, 0, stream>>>(Qg, Kg, Vtg, EKB, EVT, MB, Og);
    dim3 go(8, 32);
    k_gemm_out<<<go, 256, 0, stream>>>(Og, Wot, (float*)d_out, bo);
  }
}

// Round 5
// 313.782 us; speedup vs baseline: 1.0777x; 1.0777x over previous
//
#include <hip/hip_runtime.h>

typedef unsigned short u16;
typedef short s16x8 __attribute__((ext_vector_type(8)));
typedef float f32x4 __attribute__((ext_vector_type(4)));

#define ALPHA 0.18033688f          /* 0.125 * log2(e) : folded into Q */
#define MASKC -1.44269504e9f      /* -1e9 * log2(e) */

// ---------------- bf16 helpers (RNE) ----------------
static __device__ __forceinline__ u16 f2b(float f) {
  union { float f; unsigned u; } v; v.f = f;
  unsigned r = v.u + 0x7fffu + ((v.u >> 16) & 1u);
  return (u16)(r >> 16);
}
static __device__ __forceinline__ float b2f(u16 u) {
  union { unsigned u; float f; } v; v.u = ((unsigned)u) << 16;
  return v.f;
}
static __device__ __forceinline__ float exp2_hw(float x) {
  float r; asm("v_exp_f32 %0, %1" : "=v"(r) : "v"(x)); return r;
}

#define MFMA16(a, b, c) __builtin_amdgcn_mfma_f32_16x16x32_bf16((a), (b), (c), 0, 0, 0)

// async global -> LDS, 16B per lane (dest = uniform base + lane*16)
static __device__ __forceinline__ void gload_lds16(const u16* g, u16* l) {
  __builtin_amdgcn_global_load_lds((const __attribute__((address_space(1))) void*)g,
                                   (__attribute__((address_space(3))) void*)l, 16, 0, 0);
}

// ---------------- prep kernels ----------------
__global__ void k_cast_x(const float* __restrict__ src, u16* __restrict__ dst, int n4) {
  int i = blockIdx.x * blockDim.x + threadIdx.x;
  if (i >= n4) return;
  float4 v = ((const float4*)src)[i];
  ushort4 o;
  o.x = f2b(v.x); o.y = f2b(v.y); o.z = f2b(v.z); o.w = f2b(v.w);
  ((ushort4*)dst)[i] = o;
}

// W [1024 u][1024 n] f32 -> Wt [1024 n][1024 u] bf16
__global__ void k_transpose_w(const float* wq, const float* wk, const float* wv, const float* wo,
                              u16* dq, u16* dk, u16* dv, u16* dwo) {
  const float* src; u16* dst;
  int z = blockIdx.z;
  if (z == 0)      { src = wq; dst = dq; }
  else if (z == 1) { src = wk; dst = dk; }
  else if (z == 2) { src = wv; dst = dv; }
  else             { src = wo; dst = dwo; }
  __shared__ float t[32][33];
  int x0 = blockIdx.x * 32, y0 = blockIdx.y * 32;
  int tx = threadIdx.x, ty = threadIdx.y;
#pragma unroll
  for (int k = 0; k < 4; k++) t[ty + 8 * k][tx] = src[(size_t)(y0 + ty + 8 * k) * 1024 + x0 + tx];
  __syncthreads();
#pragma unroll
  for (int k = 0; k < 4; k++) dst[(size_t)(x0 + ty + 8 * k) * 1024 + y0 + tx] = f2b(t[tx][ty + 8 * k]);
}

// ekb: [16][144][64] bf16 ; evt: [16][64][160] bf16 (ev^T per head)
__global__ void k_prep_rel(const float* __restrict__ ek, const float* __restrict__ ev,
                           u16* __restrict__ ekb, u16* __restrict__ evt) {
  int i = blockIdx.x * blockDim.x + threadIdx.x;
  if (i < 16 * 144 * 64) {
    int h = i / (144 * 64); int rem = i % (144 * 64); int m = rem / 64; int d = rem % 64;
    ekb[i] = (m < 129) ? f2b(ek[((size_t)h * 129 + m) * 64 + d]) : (u16)0;
  }
  if (i < 16 * 64 * 160) {
    int h = i / (64 * 160); int rem = i % (64 * 160); int d = rem / 160; int mm = rem % 160;
    evt[i] = (mm < 129) ? f2b(ev[((size_t)h * 129 + mm) * 64 + d]) : (u16)0;
  }
}

// ---------------- bf16 MFMA GEMM: C[4096][1024] = A * Bt^T, 2-phase pipelined --------
// MODE 0: bf16 -> [B][H][L][D] (Q/K, scaled by oscale)
// MODE 1: bf16 -> [B][H][D][L] (V^T via operand-swapped MFMA -> coalesced)
// MODE 2: f32 row-major + bias
template <int MODE>
static __device__ __forceinline__ void gemm_body(const u16* __restrict__ A, const u16* __restrict__ Bt,
                                                 void* __restrict__ Cout, const float* __restrict__ bias,
                                                 float oscale, int bx, int by) {
  __shared__ u16 As[2][128 * 32];
  __shared__ u16 Bs[2][128 * 32];
  int tid = threadIdx.x;
  int w = tid >> 6, lane = tid & 63;
  int wrw = w >> 1, wcw = w & 1, lr = lane & 15, lk = lane >> 4;
  int m0 = by * 128, n0 = bx * 128;
  f32x4 acc[4][4] = {};
  int crow = lane >> 2;          // row within 16-row chunk
  int ccol = (lane & 3) * 8;     // u16 col within 32
  const u16* gA = &A [(size_t)(m0 + w * 32 + crow) * 1024 + ccol];
  const u16* gB = &Bt[(size_t)(n0 + w * 32 + crow) * 1024 + ccol];

  auto STAGE = [&](int buf, int k0) {
    u16* lA = &As[buf][w * 1024];
    u16* lB = &Bs[buf][w * 1024];
    gload_lds16(gA + k0,             lA);
    gload_lds16(gA + k0 + 16 * 1024, lA + 16 * 32);
    gload_lds16(gB + k0,             lB);
    gload_lds16(gB + k0 + 16 * 1024, lB + 16 * 32);
  };

  STAGE(0, 0);
  __syncthreads();
  int cur = 0;
  for (int t = 0; t < 32; t++) {
    if (t < 31) STAGE(cur ^ 1, (t + 1) * 32);
    s16x8 af[4], bfr[4];
#pragma unroll
    for (int mt = 0; mt < 4; mt++) af[mt]  = *(const s16x8*)&As[cur][(wrw * 64 + mt * 16 + lr) * 32 + lk * 8];
#pragma unroll
    for (int nt = 0; nt < 4; nt++) bfr[nt] = *(const s16x8*)&Bs[cur][(wcw * 64 + nt * 16 + lr) * 32 + lk * 8];
    __builtin_amdgcn_s_setprio(1);
#pragma unroll
    for (int mt = 0; mt < 4; mt++)
#pragma unroll
      for (int nt = 0; nt < 4; nt++) {
        if (MODE == 1) acc[mt][nt] = MFMA16(bfr[nt], af[mt], acc[mt][nt]);
        else           acc[mt][nt] = MFMA16(af[mt], bfr[nt], acc[mt][nt]);
      }
    __builtin_amdgcn_s_setprio(0);
    __syncthreads();
    cur ^= 1;
  }
#pragma unroll
  for (int mt = 0; mt < 4; mt++)
#pragma unroll
    for (int nt = 0; nt < 4; nt++)
#pragma unroll
      for (int r = 0; r < 4; r++) {
        float v = acc[mt][nt][r];
        if (MODE == 1) {
          int u = n0 + wcw * 64 + nt * 16 + lk * 4 + r;
          int l = m0 + wrw * 64 + mt * 16 + lr;
          int bb = l >> 10, ll = l & 1023;
          int hh = u >> 6, dd = u & 63;
          ((u16*)Cout)[((size_t)(bb * 16 + hh)) * 65536 + (size_t)dd * 1024 + ll] = f2b(v);
        } else {
          int row = m0 + wrw * 64 + mt * 16 + lk * 4 + r;
          int col = n0 + wcw * 64 + nt * 16 + lr;
          if (MODE == 2) {
            ((float*)Cout)[(size_t)row * 1024 + col] = v + bias[col];
          } else {
            int bb = row >> 10, l = row & 1023;
            int hh = col >> 6, dd = col & 63;
            ((u16*)Cout)[((size_t)(bb * 16 + hh)) * 65536 + (size_t)l * 64 + dd] = f2b(v * oscale);
          }
        }
      }
}

__global__ __launch_bounds__(256) void k_gemm_qk(const u16* __restrict__ A,
                                                 const u16* __restrict__ BtQ, const u16* __restrict__ BtK,
                                                 u16* __restrict__ Qo, u16* __restrict__ Ko) {
  const u16* Bt = blockIdx.z ? BtK : BtQ;
  u16* C        = blockIdx.z ? Ko  : Qo;
  gemm_body<0>(A, Bt, C, nullptr, blockIdx.z ? 1.0f : ALPHA, blockIdx.x, blockIdx.y);
}
__global__ __launch_bounds__(256) void k_gemm_v(const u16* __restrict__ A, const u16* __restrict__ Bt,
                                                u16* __restrict__ Vo) {
  gemm_body<1>(A, Bt, Vo, nullptr, 1.0f, blockIdx.x, blockIdx.y);
}
__global__ __launch_bounds__(256) void k_gemm_out(const u16* __restrict__ A, const u16* __restrict__ Bt,
                                                  float* __restrict__ Cout, const float* __restrict__ bias) {
  gemm_body<2>(A, Bt, Cout, bias, 2.0f, blockIdx.x, blockIdx.y);
}

// ---------------- fused relative-position attention ----------------
// 1 wave / 16-row q-tile, zero barriers, log2-domain softmax (Q pre-scaled by 0.125*log2e).
// Explicit software pipeline: K tile t+1 prefetched into registers while tile t computes;
// V fragments issued before the softmax VALU phase (latency hidden under exp/pack).
// LDS 15104 B:
//   qm_s   @ 0     : [16][136] bf16 = 4352
//   P_s    @ 4352  : [16][136] bf16 = 4352
//   wrb    @ 8704  : [16][136] bf16 = 4352  (buckets 0..127; bucket 128 rank-1 in epilogue)
//   mask_s @ 13056 : [1024]    bf16 = 2048  (additive mask, log2-domain)
__global__ __launch_bounds__(64) void k_attn(const u16* __restrict__ Qg, const u16* __restrict__ Kg,
                                             const u16* __restrict__ Vt, const u16* __restrict__ ekb,
                                             const u16* __restrict__ evt, const float* __restrict__ pmask,
                                             u16* __restrict__ Og) {
  __shared__ alignas(16) char smem[15104];
  u16* qm_s   = (u16*)smem;
  u16* P_s    = (u16*)(smem + 4352);
  u16* wrb    = (u16*)(smem + 8704);
  u16* mask_s = (u16*)(smem + 13056);

  int lane = threadIdx.x;
  int lr = lane & 15, lk = lane >> 4;
  // XCD-bijective swizzle (4096 % 8 == 0): blocks sharing (b,h) land on one XCD
  int wg = (blockIdx.x & 7) * 512 + (blockIdx.x >> 3);
  int bh = wg >> 6, it = wg & 63;
  int b = bh >> 4, h = bh & 15;
  int i0 = it * 16;

  // stage additive mask (bf16, log2-domain) for this batch row
  {
    const float4* pm4 = (const float4*)(pmask + (size_t)b * 1024);
#pragma unroll
    for (int t = 0; t < 4; t++) {
      float4 v = pm4[lane * 4 + t];
      unsigned w0 = (unsigned)f2b(v.x * MASKC) | ((unsigned)f2b(v.y * MASKC) << 16);
      unsigned w1 = (unsigned)f2b(v.z * MASKC) | ((unsigned)f2b(v.w * MASKC) << 16);
      ((unsigned*)mask_s)[lane * 8 + t * 2]     = w0;
      ((unsigned*)mask_s)[lane * 8 + t * 2 + 1] = w1;
    }
  }
  // zero wrb
  for (int t = lane; t < 1088; t += 64) ((unsigned*)wrb)[t] = 0u;

  // Q fragments (pre-scaled by ALPHA at GEMM epilogue)
  const u16* qp = &Qg[((size_t)bh * 1024 + i0 + lr) * 64 + lk * 8];
  s16x8 aq0 = *(const s16x8*)qp;
  s16x8 aq1 = *(const s16x8*)(qp + 32);

  // qm[i][m] = q_i . ek[h][m] (log2-domain)
#pragma unroll
  for (int nt = 0; nt < 9; nt++) {
    f32x4 c = {};
    const u16* ekp = &ekb[((size_t)h * 144 + nt * 16 + lr) * 64 + lk * 8];
    c = MFMA16(aq0, *(const s16x8*)ekp, c);
    c = MFMA16(aq1, *(const s16x8*)(ekp + 32), c);
    int mcol = nt * 16 + lr;
    if (mcol < 129) {
#pragma unroll
      for (int r = 0; r < 4; r++) qm_s[(lk * 4 + r) * 136 + mcol] = f2b(c[r]);
    }
  }

  float ssum = 0.f, lsum = 0.f, rsum = 0.f;
  f32x4 oacc[4] = {};
  const int ig = i0 + lr;
  const u16* Kt  = Kg + (size_t)bh * 65536 + (size_t)lr * 64 + lk * 8;
  const u16* Vt0 = Vt + (size_t)bh * 65536 + (size_t)lr * 1024 + lk * 8;

  // K register double-buffer: kbuf[buf][nt*2+half]
  s16x8 kbuf[2][16];
#pragma unroll
  for (int i = 0; i < 16; i++)
    kbuf[0][i] = *(const s16x8*)(Kt + (i >> 1) * 16 * 64 + (i & 1) * 32);

#pragma unroll
  for (int jt = 0; jt < 8; jt++) {
    const int j0 = jt * 128;
    const int cur = jt & 1;
    // ---- QK^T (swapped: rows=j, cols=i) from current K registers ----
    f32x4 c[8];
#pragma unroll
    for (int nt = 0; nt < 8; nt++) {
      f32x4 cc = {};
      cc = MFMA16(kbuf[cur][nt * 2],     aq0, cc);
      cc = MFMA16(kbuf[cur][nt * 2 + 1], aq1, cc);
      c[nt] = cc;
    }
    // ---- prefetch next K tile into the other buffer ----
    if (jt < 7) {
      const u16* kn = Kt + (size_t)(j0 + 128) * 64;
#pragma unroll
      for (int i = 0; i < 16; i++)
        kbuf[cur ^ 1][i] = *(const s16x8*)(kn + (i >> 1) * 16 * 64 + (i & 1) * 32);
    }
    // ---- issue V fragments for this tile (consumed after softmax) ----
    s16x8 vf[16];
#pragma unroll
    for (int i = 0; i < 16; i++)
      vf[i] = *(const s16x8*)(Vt0 + (i >> 2) * 16 * 1024 + j0 + (i & 3) * 32);

    // ---- softmax VALU phase: qm gather + mask + exp2, pack to LDS ----
    float p[8][4];
#pragma unroll
    for (int nt = 0; nt < 8; nt++) {
      ushort4 mv = *(const ushort4*)&mask_s[j0 + nt * 16 + lk * 4];
#pragma unroll
      for (int r = 0; r < 4; r++) {
        int dl = j0 + nt * 16 + lk * 4 + r - ig;
        dl = dl < -64 ? -64 : (dl > 64 ? 64 : dl);
        float qmv = b2f(qm_s[lr * 136 + dl + 64]);
        float mr = b2f(r == 0 ? mv.x : r == 1 ? mv.y : r == 2 ? mv.z : mv.w);
        p[nt][r] = exp2_hw(c[nt][r] + qmv + mr);
      }
      unsigned lo, hi;
      asm("v_cvt_pk_bf16_f32 %0, %1, %2" : "=v"(lo) : "v"(p[nt][0]), "v"(p[nt][1]));
      asm("v_cvt_pk_bf16_f32 %0, %1, %2" : "=v"(hi) : "v"(p[nt][2]), "v"(p[nt][3]));
      uint2 pk; pk.x = lo; pk.y = hi;
      *(uint2*)&P_s[lr * 136 + nt * 16 + lk * 4] = pk;
    }
    // ---- row-sum (tree) ----
    {
      float t0 = 0.f, t1 = 0.f, t2 = 0.f, t3 = 0.f;
#pragma unroll
      for (int nt = 0; nt < 8; nt++) { t0 += p[nt][0]; t1 += p[nt][1]; t2 += p[nt][2]; t3 += p[nt][3]; }
      float tsum = (t0 + t1) + (t2 + t3);
      ssum += tsum;
      // ---- route P mass to relative buckets ----
      if (j0 <= i0 - 191) {          // tile fully left of band (all dl <= -64)
        lsum += tsum;
      } else if (j0 >= i0 + 79) {    // tile fully right (all dl >= 64)
        rsum += tsum;
      } else {
#pragma unroll
        for (int nt = 0; nt < 8; nt++)
#pragma unroll
          for (int r = 0; r < 4; r++) {
            float pv = p[nt][r];
            int dl = j0 + nt * 16 + lk * 4 + r - ig;
            if (dl <= -64) lsum += pv;
            else if (dl >= 64) rsum += pv;
            else wrb[lr * 136 + dl + 64] = f2b(pv);
          }
      }
    }
    // ---- PV: oacc[i][d] += P~ . V ----
    __builtin_amdgcn_s_setprio(1);
    {
      s16x8 ap[4];
#pragma unroll
      for (int kk = 0; kk < 4; kk++) ap[kk] = *(const s16x8*)&P_s[lr * 136 + kk * 32 + lk * 8];
#pragma unroll
      for (int nt = 0; nt < 4; nt++)
#pragma unroll
        for (int kk = 0; kk < 4; kk++)
          oacc[nt] = MFMA16(ap[kk], vf[nt * 4 + kk], oacc[nt]);
    }
    __builtin_amdgcn_s_setprio(0);
  }

  // reduce edge/total sums across the 4 lanes sharing lr
  lsum += __shfl_xor(lsum, 16); lsum += __shfl_xor(lsum, 32);
  rsum += __shfl_xor(rsum, 16); rsum += __shfl_xor(rsum, 32);
  ssum += __shfl_xor(ssum, 16); ssum += __shfl_xor(ssum, 32);
  if (lk == 0) wrb[lr * 136] = f2b(lsum);   // bucket 0

  // oacc += wr . Ev over buckets 0..127
  __builtin_amdgcn_s_setprio(1);
  {
    s16x8 aw[4];
#pragma unroll
    for (int kk = 0; kk < 4; kk++) aw[kk] = *(const s16x8*)&wrb[lr * 136 + kk * 32 + lk * 8];
    const u16* ebase = &evt[((size_t)h * 64 + lr) * 160 + lk * 8];
#pragma unroll
    for (int nt = 0; nt < 4; nt++) {
      const u16* ep = ebase + nt * 16 * 160;
#pragma unroll
      for (int kk = 0; kk < 4; kk++)
        oacc[nt] = MFMA16(aw[kk], *(const s16x8*)(ep + kk * 32), oacc[nt]);
    }
  }
  __builtin_amdgcn_s_setprio(0);

  // bucket 128 rank-1: oacc[i][d] += rsum[i] * ev[h][128][d]
  {
    float rs[4];
#pragma unroll
    for (int r = 0; r < 4; r++) rs[r] = __shfl(rsum, lk * 4 + r);
#pragma unroll
    for (int nt = 0; nt < 4; nt++) {
      float evc = b2f(evt[((size_t)h * 64 + nt * 16 + lr) * 160 + 128]);
#pragma unroll
      for (int r = 0; r < 4; r++) oacc[nt][r] += rs[r] * evc;
    }
  }

  // normalize + write O[(b,l)][(h,d)]
  float rden[4];
#pragma unroll
  for (int r = 0; r < 4; r++) rden[r] = 1.0f / __shfl(ssum, lk * 4 + r);
  u16* obase = &Og[((size_t)(b * 1024 + i0)) * 1024 + h * 64];
#pragma unroll
  for (int nt = 0; nt < 4; nt++)
#pragma unroll
    for (int r = 0; r < 4; r++) {
      int il = lk * 4 + r;
      obase[(size_t)il * 1024 + nt * 16 + lr] = f2b(oacc[nt][r] * rden[r]);
    }
}

// ---------------- launch ----------------
#define OFF_XB   0u
#define OFF_WQT  8388608u
#define OFF_WKT  10485760u
#define OFF_WVT  12582912u
#define OFF_WOT  14680064u
#define OFF_Q    16777216u
#define OFF_K    25165824u
#define OFF_VT   33554432u
#define OFF_O    41943040u
#define OFF_EKB  50331648u
#define OFF_EVT  50626560u

extern "C" void kernel_launch(void* const* d_in, const int* in_sizes, int n_in,
                              void* d_out, int out_size, void* d_ws, size_t ws_size,
                              hipStream_t stream) {
  const float* x  = (const float*)d_in[0];
  const float* pm = (const float*)d_in[1];
  const float* wq = (const float*)d_in[2];
  const float* wk = (const float*)d_in[3];
  const float* wv = (const float*)d_in[4];
  const float* wo = (const float*)d_in[5];
  const float* bo = (const float*)d_in[6];
  const float* ek = (const float*)d_in[7];
  const float* ev = (const float*)d_in[8];
  char* ws = (char*)d_ws;
  u16* Xb  = (u16*)(ws + OFF_XB);
  u16* Wqt = (u16*)(ws + OFF_WQT);
  u16* Wkt = (u16*)(ws + OFF_WKT);
  u16* Wvt = (u16*)(ws + OFF_WVT);
  u16* Wot = (u16*)(ws + OFF_WOT);
  u16* Qg  = (u16*)(ws + OFF_Q);
  u16* Kg  = (u16*)(ws + OFF_K);
  u16* Vtg = (u16*)(ws + OFF_VT);
  u16* Og  = (u16*)(ws + OFF_O);
  u16* EKB = (u16*)(ws + OFF_EKB);
  u16* EVT = (u16*)(ws + OFF_EVT);

  k_cast_x<<<4096, 256, 0, stream>>>(x, Xb, 1048576);
  {
    dim3 tb(32, 8), tg(32, 32, 4);
    k_transpose_w<<<tg, tb, 0, stream>>>(wq, wk, wv, wo, Wqt, Wkt, Wvt, Wot);
  }
  k_prep_rel<<<640, 256, 0, stream>>>(ek, ev, EKB, EVT);
  {
    dim3 gqk(8, 32, 2);
    k_gemm_qk<<<gqk, 256, 0, stream>>>(Xb, Wqt, Wkt, Qg, Kg);
    dim3 gv(8, 32);
    k_gemm_v<<<gv, 256, 0, stream>>>(Xb, Wvt, Vtg);
    k_attn<<<4096, 64, 0, stream>>>(Qg, Kg, Vtg, EKB, EVT, pm, Og);
    dim3 go(8, 32);
    k_gemm_out<<<go, 256, 0, stream>>>(Og, Wot, (float*)d_out, bo);
  }
}

// Round 8
// 313.160 us; speedup vs baseline: 1.0799x; 1.0020x over previous
//
#include <hip/hip_runtime.h>

typedef unsigned short u16;
typedef short s16x8 __attribute__((ext_vector_type(8)));
typedef float f32x4 __attribute__((ext_vector_type(4)));

#define ALPHA 0.18033688f          /* 0.125 * log2(e) : folded into Q */
#define MASKC -1.44269504e9f      /* -1e9 * log2(e) */

// ---------------- bf16 helpers (RNE) ----------------
static __device__ __forceinline__ u16 f2b(float f) {
  union { float f; unsigned u; } v; v.f = f;
  unsigned r = v.u + 0x7fffu + ((v.u >> 16) & 1u);
  return (u16)(r >> 16);
}
static __device__ __forceinline__ float b2f(u16 u) {
  union { unsigned u; float f; } v; v.u = ((unsigned)u) << 16;
  return v.f;
}
static __device__ __forceinline__ float exp2_hw(float x) {
  float r; asm("v_exp_f32 %0, %1" : "=v"(r) : "v"(x)); return r;
}

#define MFMA16(a, b, c) __builtin_amdgcn_mfma_f32_16x16x32_bf16((a), (b), (c), 0, 0, 0)

// async global -> LDS, 16B per lane (dest = uniform base + lane*16)
static __device__ __forceinline__ void gload_lds16(const u16* g, u16* l) {
  __builtin_amdgcn_global_load_lds((const __attribute__((address_space(1))) void*)g,
                                   (__attribute__((address_space(3))) void*)l, 16, 0, 0);
}

// ---------------- merged prep: cast x, transpose weights, rel embeddings ----------------
// blocks 0..4095: cast x -> bf16 ; 4096..8191: transpose 4 weights ; 8192..8831: ek/ev prep
__global__ __launch_bounds__(256) void k_prep(const float* __restrict__ x,
                                              const float* wq, const float* wk, const float* wv, const float* wo,
                                              const float* __restrict__ ek, const float* __restrict__ ev,
                                              u16* __restrict__ xb,
                                              u16* dq, u16* dk, u16* dv, u16* dwo,
                                              u16* __restrict__ ekb, u16* __restrict__ evt) {
  __shared__ float t[32][33];
  int bid = blockIdx.x, tid = threadIdx.x;
  if (bid < 4096) {
    int i = bid * 256 + tid;
    float4 v = ((const float4*)x)[i];
    ushort4 o;
    o.x = f2b(v.x); o.y = f2b(v.y); o.z = f2b(v.z); o.w = f2b(v.w);
    ((ushort4*)xb)[i] = o;
  } else if (bid < 8192) {
    int bb = bid - 4096;
    int z = bb >> 10, rem = bb & 1023;
    int x0 = (rem & 31) * 32, y0 = (rem >> 5) * 32;
    const float* src; u16* dst;
    if (z == 0)      { src = wq; dst = dq; }
    else if (z == 1) { src = wk; dst = dk; }
    else if (z == 2) { src = wv; dst = dv; }
    else             { src = wo; dst = dwo; }
    int tx = tid & 31, ty = tid >> 5;
#pragma unroll
    for (int k = 0; k < 4; k++) t[ty + 8 * k][tx] = src[(size_t)(y0 + ty + 8 * k) * 1024 + x0 + tx];
    __syncthreads();
#pragma unroll
    for (int k = 0; k < 4; k++) dst[(size_t)(x0 + ty + 8 * k) * 1024 + y0 + tx] = f2b(t[tx][ty + 8 * k]);
  } else {
    int i = (bid - 8192) * 256 + tid;
    if (i < 16 * 144 * 64) {
      int h = i / (144 * 64); int rem = i % (144 * 64); int m = rem / 64; int d = rem % 64;
      ekb[i] = (m < 129) ? f2b(ek[((size_t)h * 129 + m) * 64 + d]) : (u16)0;
    }
    if (i < 16 * 64 * 160) {
      int h = i / (64 * 160); int rem = i % (64 * 160); int d = rem / 160; int mm = rem % 160;
      evt[i] = (mm < 129) ? f2b(ev[((size_t)h * 129 + mm) * 64 + d]) : (u16)0;
    }
  }
}

// ---------------- bf16 MFMA GEMM: C[4096][1024] = A * Bt^T, 2-phase pipelined --------
// MODE 0: bf16 -> [B][H][L][D] (Q/K, scaled by oscale)
// MODE 1: bf16 -> [B][H][D][L] (V^T via operand-swapped MFMA -> coalesced)
// MODE 2: f32 row-major + bias
template <int MODE>
static __device__ __forceinline__ void gemm_body(const u16* __restrict__ A, const u16* __restrict__ Bt,
                                                 void* __restrict__ Cout, const float* __restrict__ bias,
                                                 float oscale, int bx, int by) {
  __shared__ u16 As[2][128 * 32];
  __shared__ u16 Bs[2][128 * 32];
  int tid = threadIdx.x;
  int w = tid >> 6, lane = tid & 63;
  int wrw = w >> 1, wcw = w & 1, lr = lane & 15, lk = lane >> 4;
  int m0 = by * 128, n0 = bx * 128;
  f32x4 acc[4][4] = {};
  int crow = lane >> 2;
  int ccol = (lane & 3) * 8;
  const u16* gA = &A [(size_t)(m0 + w * 32 + crow) * 1024 + ccol];
  const u16* gB = &Bt[(size_t)(n0 + w * 32 + crow) * 1024 + ccol];

  auto STAGE = [&](int buf, int k0) {
    u16* lA = &As[buf][w * 1024];
    u16* lB = &Bs[buf][w * 1024];
    gload_lds16(gA + k0,             lA);
    gload_lds16(gA + k0 + 16 * 1024, lA + 16 * 32);
    gload_lds16(gB + k0,             lB);
    gload_lds16(gB + k0 + 16 * 1024, lB + 16 * 32);
  };

  STAGE(0, 0);
  __syncthreads();
  int cur = 0;
  for (int t = 0; t < 32; t++) {
    if (t < 31) STAGE(cur ^ 1, (t + 1) * 32);
    s16x8 af[4], bfr[4];
#pragma unroll
    for (int mt = 0; mt < 4; mt++) af[mt]  = *(const s16x8*)&As[cur][(wrw * 64 + mt * 16 + lr) * 32 + lk * 8];
#pragma unroll
    for (int nt = 0; nt < 4; nt++) bfr[nt] = *(const s16x8*)&Bs[cur][(wcw * 64 + nt * 16 + lr) * 32 + lk * 8];
    __builtin_amdgcn_s_setprio(1);
#pragma unroll
    for (int mt = 0; mt < 4; mt++)
#pragma unroll
      for (int nt = 0; nt < 4; nt++) {
        if (MODE == 1) acc[mt][nt] = MFMA16(bfr[nt], af[mt], acc[mt][nt]);
        else           acc[mt][nt] = MFMA16(af[mt], bfr[nt], acc[mt][nt]);
      }
    __builtin_amdgcn_s_setprio(0);
    __syncthreads();
    cur ^= 1;
  }
#pragma unroll
  for (int mt = 0; mt < 4; mt++)
#pragma unroll
    for (int nt = 0; nt < 4; nt++)
#pragma unroll
      for (int r = 0; r < 4; r++) {
        float v = acc[mt][nt][r];
        if (MODE == 1) {
          int u = n0 + wcw * 64 + nt * 16 + lk * 4 + r;
          int l = m0 + wrw * 64 + mt * 16 + lr;
          int bb = l >> 10, ll = l & 1023;
          int hh = u >> 6, dd = u & 63;
          ((u16*)Cout)[((size_t)(bb * 16 + hh)) * 65536 + (size_t)dd * 1024 + ll] = f2b(v);
        } else {
          int row = m0 + wrw * 64 + mt * 16 + lk * 4 + r;
          int col = n0 + wcw * 64 + nt * 16 + lr;
          if (MODE == 2) {
            ((float*)Cout)[(size_t)row * 1024 + col] = v + bias[col];
          } else {
            int bb = row >> 10, l = row & 1023;
            int hh = col >> 6, dd = col & 63;
            ((u16*)Cout)[((size_t)(bb * 16 + hh)) * 65536 + (size_t)l * 64 + dd] = f2b(v * oscale);
          }
        }
      }
}

__global__ __launch_bounds__(256) void k_gemm_qkv(const u16* __restrict__ A,
                                                  const u16* __restrict__ BtQ, const u16* __restrict__ BtK,
                                                  const u16* __restrict__ BtV,
                                                  u16* __restrict__ Qo, u16* __restrict__ Ko,
                                                  u16* __restrict__ Vo) {
  int z = blockIdx.z;
  if (z == 0)      gemm_body<0>(A, BtQ, Qo, nullptr, ALPHA, blockIdx.x, blockIdx.y);
  else if (z == 1) gemm_body<0>(A, BtK, Ko, nullptr, 1.0f,  blockIdx.x, blockIdx.y);
  else             gemm_body<1>(A, BtV, Vo, nullptr, 1.0f,  blockIdx.x, blockIdx.y);
}
__global__ __launch_bounds__(256) void k_gemm_out(const u16* __restrict__ A, const u16* __restrict__ Bt,
                                                  float* __restrict__ Cout, const float* __restrict__ bias) {
  gemm_body<2>(A, Bt, Cout, bias, 1.0f, blockIdx.x, blockIdx.y);
}

// ---------------- fused relative-position attention ----------------
// 4 waves / 16-row q-tile; wave w handles 64-wide j-tiles {w, w+4, w+8, w+12}.
// Swapped QK^T (lane owns row i=lr); skewed qm storage with LOCAL row index:
//   qm_skew[i_loc][(m + i_loc - 64) mod 144] = qm[i_loc][m]
//   => in-band read column = ((j - i0) mod 144)   (FIX r7: was j mod 144 — wrong for i0>0)
// Swizzled P round-trip; oacc/sum merge via LDS; wave 0 runs the wr.Ev epilogue.
// LDS 21504 B:
//   union  @ 0     : 16384  { qm_skew[16][144] u16 @0 ; P_w[16][64] u16 swz @4608+w*2048 }
//                           -> overlaid by oacc dump [4][64][16] f32 after barrier
//   wrb    @ 16384 : [16][136] bf16 = 4352 (buckets 0..127; 128 via rank-1)
//   sums   @ 20736 : [3][64] f32 = 768 (ssum/lsum/rsum per (wave,row))
__global__ __launch_bounds__(256) void k_attn(const u16* __restrict__ Qg, const u16* __restrict__ Kg,
                                              const u16* __restrict__ Vt, const u16* __restrict__ ekb,
                                              const u16* __restrict__ evt, const float* __restrict__ pmask,
                                              u16* __restrict__ Og) {
  __shared__ alignas(16) char smem[21504];
  u16*   qm_skew = (u16*)smem;
  u16*   wrb     = (u16*)(smem + 16384);
  float* sums    = (float*)(smem + 20736);

  int tid = threadIdx.x;
  int w = tid >> 6, lane = tid & 63;
  int lr = lane & 15, lk = lane >> 4;
  // XCD-bijective swizzle (4096 % 8 == 0): blocks sharing (b,h) land on one XCD
  int wg = (blockIdx.x & 7) * 512 + (blockIdx.x >> 3);
  int bh = wg >> 6, it = wg & 63;
  int b = bh >> 4, h = bh & 15;
  int i0 = it * 16;
  const int ig = i0 + lr;
  char* P_w = smem + 4608 + w * 2048;

  // zero wrb cooperatively
  for (int t = tid; t < 1088; t += 256) ((unsigned*)wrb)[t] = 0u;

  // Q fragments (pre-scaled by ALPHA at GEMM epilogue)
  const u16* qp = &Qg[((size_t)bh * 1024 + i0 + lr) * 64 + lk * 8];
  s16x8 aq0 = *(const s16x8*)qp;
  s16x8 aq1 = *(const s16x8*)(qp + 32);

  // qm[i][m] = q_i . ek[h][m], nt-split across waves, stored SKEWED (local row i):
  // qm_skew[i][(m + i - 64) mod 144]  => in-band read at col ((j - i0) mod 144)
  {
    int nts = (w == 0) ? 0 : 2 * w + 1;
    int nte = (w == 0) ? 3 : 2 * w + 3;
    for (int nt = nts; nt < nte; nt++) {
      f32x4 c = {};
      const u16* ekp = &ekb[((size_t)h * 144 + nt * 16 + lr) * 64 + lk * 8];
      c = MFMA16(aq0, *(const s16x8*)ekp, c);
      c = MFMA16(aq1, *(const s16x8*)(ekp + 32), c);
      int m = nt * 16 + lr;
      if (m < 129) {
#pragma unroll
        for (int r = 0; r < 4; r++) {
          int i = lk * 4 + r;
          int col = m + i - 64; if (col < 0) col += 144;
          qm_skew[i * 144 + col] = f2b(c[r]);
        }
      }
    }
  }
  __syncthreads();   // B0: wrb zeroed, qm_skew complete

  float qmL = b2f(qm_skew[lr * 144 + lr + 80]);   // m=0   at col (0+lr-64)+144
  float qmR = b2f(qm_skew[lr * 144 + lr + 64]);   // m=128 at col 128+lr-64

  float ssum = 0.f, lsum = 0.f, rsum = 0.f;
  f32x4 oacc[4] = {};
  const u16* Kt  = Kg + (size_t)bh * 65536 + (size_t)lr * 64 + lk * 8;
  const u16* Vt0 = Vt + (size_t)bh * 65536 + (size_t)lr * 1024 + lk * 8;
  const float* pmb = pmask + b * 1024;

  // prologue: K,V for this wave's first tile
  s16x8 kbuf[8], vf[8];
  {
    const u16* kp = Kt + (size_t)(w * 64) * 64;
#pragma unroll
    for (int i = 0; i < 8; i++) kbuf[i] = *(const s16x8*)(kp + (i >> 1) * 16 * 64 + (i & 1) * 32);
#pragma unroll
    for (int i = 0; i < 8; i++) vf[i] = *(const s16x8*)(Vt0 + (i >> 1) * 16 * 1024 + w * 64 + (i & 1) * 32);
  }

#pragma unroll
  for (int t = 0; t < 4; t++) {
    const int j0c = (w + t * 4) * 64;
    // mask (broadcast float4 from L2)
    float4 mv[4];
#pragma unroll
    for (int nt = 0; nt < 4; nt++) mv[nt] = *(const float4*)&pmb[j0c + nt * 16 + lk * 4];
    // ---- QK^T (swapped: rows=j, cols=i) ----
    f32x4 c[4];
#pragma unroll
    for (int nt = 0; nt < 4; nt++) {
      f32x4 cc = {};
      cc = MFMA16(kbuf[nt * 2],     aq0, cc);
      cc = MFMA16(kbuf[nt * 2 + 1], aq1, cc);
      c[nt] = cc;
    }
    // ---- prefetch next K (same regs; WAR after MFMA issue) ----
    if (t < 3) {
      const u16* kp = Kt + (size_t)(j0c + 256) * 64;
#pragma unroll
      for (int i = 0; i < 8; i++) kbuf[i] = *(const s16x8*)(kp + (i >> 1) * 16 * 64 + (i & 1) * 32);
    }
    // ---- softmax: skewed qm read + mask + exp2, pack to swizzled P ----
    unsigned j0m = (unsigned)(j0c - i0 + 1152) % 144u;   // FIX: column base is (j - i0) mod 144
    float p[4][4];
#pragma unroll
    for (int nt = 0; nt < 4; nt++) {
      int colb = (int)j0m + nt * 16 + lk * 4; if (colb >= 144) colb -= 144;
      ushort4 qv = *(const ushort4*)&qm_skew[lr * 144 + colb];
#pragma unroll
      for (int r = 0; r < 4; r++) {
        int dl = j0c + nt * 16 + lk * 4 + r - ig;
        float qs = b2f(r == 0 ? qv.x : r == 1 ? qv.y : r == 2 ? qv.z : qv.w);
        float qmv = (dl > -64 && dl < 64) ? qs : (dl <= -64 ? qmL : qmR);
        float mr = (r == 0 ? mv[nt].x : r == 1 ? mv[nt].y : r == 2 ? mv[nt].z : mv[nt].w) * MASKC;
        p[nt][r] = exp2_hw(c[nt][r] + qmv + mr);
      }
      unsigned lo, hi;
      asm("v_cvt_pk_bf16_f32 %0, %1, %2" : "=v"(lo) : "v"(p[nt][0]), "v"(p[nt][1]));
      asm("v_cvt_pk_bf16_f32 %0, %1, %2" : "=v"(hi) : "v"(p[nt][2]), "v"(p[nt][3]));
      uint2 pk; pk.x = lo; pk.y = hi;
      unsigned off = (unsigned)(lr * 128 + (nt * 16 + lk * 4) * 2) ^ (unsigned)((lr & 7) << 4);
      *(uint2*)(P_w + off) = pk;
    }
    // ---- sums + bucket routing ----
    {
      float t0 = 0.f, t1 = 0.f, t2 = 0.f, t3 = 0.f;
#pragma unroll
      for (int nt = 0; nt < 4; nt++) { t0 += p[nt][0]; t1 += p[nt][1]; t2 += p[nt][2]; t3 += p[nt][3]; }
      float tsum = (t0 + t1) + (t2 + t3);
      ssum += tsum;
      if (j0c <= i0 - 127) {            // tile fully left of band
        lsum += tsum;
      } else if (j0c >= i0 + 79) {      // tile fully right
        rsum += tsum;
      } else {
#pragma unroll
        for (int nt = 0; nt < 4; nt++)
#pragma unroll
          for (int r = 0; r < 4; r++) {
            float pv = p[nt][r];
            int dl = j0c + nt * 16 + lk * 4 + r - ig;
            if (dl <= -64) lsum += pv;
            else if (dl >= 64) rsum += pv;
            else wrb[lr * 136 + dl + 64] = f2b(pv);
          }
      }
    }
    // ---- PV ----
    s16x8 ap[2];
#pragma unroll
    for (int kk = 0; kk < 2; kk++) {
      unsigned off = (unsigned)(lr * 128 + (kk * 32 + lk * 8) * 2) ^ (unsigned)((lr & 7) << 4);
      ap[kk] = *(const s16x8*)(P_w + off);
    }
    __builtin_amdgcn_s_setprio(1);
#pragma unroll
    for (int nd = 0; nd < 4; nd++)
#pragma unroll
      for (int kk = 0; kk < 2; kk++)
        oacc[nd] = MFMA16(ap[kk], vf[nd * 2 + kk], oacc[nd]);
    __builtin_amdgcn_s_setprio(0);
    // ---- prefetch next V ----
    if (t < 3) {
#pragma unroll
      for (int i = 0; i < 8; i++)
        vf[i] = *(const s16x8*)(Vt0 + (i >> 1) * 16 * 1024 + (j0c + 256) + (i & 1) * 32);
    }
  }

  // per-wave reduce over the 4 lanes sharing lr
  lsum += __shfl_xor(lsum, 16); lsum += __shfl_xor(lsum, 32);
  rsum += __shfl_xor(rsum, 16); rsum += __shfl_xor(rsum, 32);
  ssum += __shfl_xor(ssum, 16); ssum += __shfl_xor(ssum, 32);
  if (lk == 0) {
    sums[w * 16 + lr]       = ssum;
    sums[64 + w * 16 + lr]  = lsum;
    sums[128 + w * 16 + lr] = rsum;
  }
  __syncthreads();   // B1: all tiles done (wrb complete, qm/P dead)

  // dump partial oacc into the union region
  {
    float* dump = (float*)smem + w * 1024 + lane * 16;
#pragma unroll
    for (int nd = 0; nd < 4; nd++) *(f32x4*)(dump + nd * 4) = oacc[nd];
  }
  __syncthreads();   // B2
  if (w != 0) return;

  // ---- wave 0 epilogue: merge + wr.Ev + rank-1 + normalize + write ----
#pragma unroll
  for (int ww = 1; ww < 4; ww++) {
    const float* dump = (const float*)smem + ww * 1024 + lane * 16;
#pragma unroll
    for (int nd = 0; nd < 4; nd++) oacc[nd] += *(const f32x4*)(dump + nd * 4);
  }
  float ssr = 0.f, lsr = 0.f, rsr = 0.f;
#pragma unroll
  for (int ww = 0; ww < 4; ww++) {
    ssr += sums[ww * 16 + lr];
    lsr += sums[64 + ww * 16 + lr];
    rsr += sums[128 + ww * 16 + lr];
  }
  if (lk == 0) wrb[lr * 136] = f2b(lsr);   // bucket 0

  // oacc += wr . Ev over buckets 0..127
  __builtin_amdgcn_s_setprio(1);
  {
    s16x8 aw[4];
#pragma unroll
    for (int kk = 0; kk < 4; kk++) aw[kk] = *(const s16x8*)&wrb[lr * 136 + kk * 32 + lk * 8];
    const u16* ebase = &evt[((size_t)h * 64 + lr) * 160 + lk * 8];
#pragma unroll
    for (int nt = 0; nt < 4; nt++) {
      const u16* ep = ebase + nt * 16 * 160;
#pragma unroll
      for (int kk = 0; kk < 4; kk++)
        oacc[nt] = MFMA16(aw[kk], *(const s16x8*)(ep + kk * 32), oacc[nt]);
    }
  }
  __builtin_amdgcn_s_setprio(0);

  // bucket 128 rank-1: oacc[i][d] += rsum[i] * ev[h][128][d]
  {
    float rs[4];
#pragma unroll
    for (int r = 0; r < 4; r++) rs[r] = __shfl(rsr, lk * 4 + r);
#pragma unroll
    for (int nt = 0; nt < 4; nt++) {
      float evc = b2f(evt[((size_t)h * 64 + nt * 16 + lr) * 160 + 128]);
#pragma unroll
      for (int r = 0; r < 4; r++) oacc[nt][r] += rs[r] * evc;
    }
  }

  // normalize + write O[(b,l)][(h,d)]
  float rden[4];
#pragma unroll
  for (int r = 0; r < 4; r++) rden[r] = 1.0f / __shfl(ssr, lk * 4 + r);
  u16* obase = &Og[((size_t)(b * 1024 + i0)) * 1024 + h * 64];
#pragma unroll
  for (int nt = 0; nt < 4; nt++)
#pragma unroll
    for (int r = 0; r < 4; r++) {
      int il = lk * 4 + r;
      obase[(size_t)il * 1024 + nt * 16 + lr] = f2b(oacc[nt][r] * rden[r]);
    }
}

// ---------------- launch ----------------
#define OFF_XB   0u
#define OFF_WQT  8388608u
#define OFF_WKT  10485760u
#define OFF_WVT  12582912u
#define OFF_WOT  14680064u
#define OFF_Q    16777216u
#define OFF_K    25165824u
#define OFF_VT   33554432u
#define OFF_O    41943040u
#define OFF_EKB  50331648u
#define OFF_EVT  50626560u

extern "C" void kernel_launch(void* const* d_in, const int* in_sizes, int n_in,
                              void* d_out, int out_size, void* d_ws, size_t ws_size,
                              hipStream_t stream) {
  const float* x  = (const float*)d_in[0];
  const float* pm = (const float*)d_in[1];
  const float* wq = (const float*)d_in[2];
  const float* wk = (const float*)d_in[3];
  const float* wv = (const float*)d_in[4];
  const float* wo = (const float*)d_in[5];
  const float* bo = (const float*)d_in[6];
  const float* ek = (const float*)d_in[7];
  const float* ev = (const float*)d_in[8];
  char* ws = (char*)d_ws;
  u16* Xb  = (u16*)(ws + OFF_XB);
  u16* Wqt = (u16*)(ws + OFF_WQT);
  u16* Wkt = (u16*)(ws + OFF_WKT);
  u16* Wvt = (u16*)(ws + OFF_WVT);
  u16* Wot = (u16*)(ws + OFF_WOT);
  u16* Qg  = (u16*)(ws + OFF_Q);
  u16* Kg  = (u16*)(ws + OFF_K);
  u16* Vtg = (u16*)(ws + OFF_VT);
  u16* Og  = (u16*)(ws + OFF_O);
  u16* EKB = (u16*)(ws + OFF_EKB);
  u16* EVT = (u16*)(ws + OFF_EVT);

  k_prep<<<8832, 256, 0, stream>>>(x, wq, wk, wv, wo, ek, ev, Xb, Wqt, Wkt, Wvt, Wot, EKB, EVT);
  {
    dim3 gq(8, 32, 3);
    k_gemm_qkv<<<gq, 256, 0, stream>>>(Xb, Wqt, Wkt, Wvt, Qg, Kg, Vtg);
    k_attn<<<4096, 256, 0, stream>>>(Qg, Kg, Vtg, EKB, EVT, pm, Og);
    dim3 go(8, 32);
    k_gemm_out<<<go, 256, 0, stream>>>(Og, Wot, (float*)d_out, bo);
  }
}